// Round 17
// baseline (276.016 us; speedup 1.0000x reference)
//
#include <hip/hip_runtime.h>

// B=256, N=512 cells, G=117 genes, CH=25 conv channels.
// WAVE-SPECIALIZED: one block = one batch, grid 256 = 1 block/CU, 768 threads
// = 12 waves. Waves 0-7: r12's verified compute (conv-as-MFMA, register
// handoff via cvt_pk+permlane32_swap, mega-slab LDS weights, zero-barrier
// 10-jt runs, direct-register cell stores). Waves 8-11: DEDICATED out1
// streamer waves that write the 61 MB glob-broadcast during the two compute
// runs (fillBuffer-style store-only waves saturate HBM independently of the
// compute schedule). Spot from registers; one epilogue barrier.

typedef __attribute__((ext_vector_type(16))) float f32x16;
typedef __attribute__((ext_vector_type(8))) short short8;
typedef __attribute__((ext_vector_type(2))) unsigned int uint2v;
typedef __attribute__((ext_vector_type(4))) unsigned int uint4v;

#define WCOMB_OFF 0          // 245760 B : [20 jt][12288 B = 4KB a | 8KB wb]
#define GLOB_OFF  245760     // 1024 B   : glob[256]

#define SPOT_OUT_OFF 0
#define CELL_OUT_OFF 29952
#define OUT1_OUT_OFF 15365376

#define SMEM_BYTES 155648    // imgbs 32768 + wslab 122880

__device__ __forceinline__ unsigned short f2bf(float x) {
  unsigned int u = __builtin_bit_cast(unsigned int, x);
  u = (u + 0x7FFFu + ((u >> 16) & 1u)) >> 16;   // RNE
  return (unsigned short)u;
}

__device__ __forceinline__ unsigned int cvt_pk_bf16(float lo, float hi) {
  unsigned int w;
  asm("v_cvt_pk_bf16_f32 %0, %1, %2" : "=v"(w) : "v"(lo), "v"(hi));
  return w;
}

__device__ __forceinline__ void gload16(const void* g, void* l) {
  __builtin_amdgcn_global_load_lds(
      (const __attribute__((address_space(1))) void*)g,
      (__attribute__((address_space(3))) void*)l, 16, 0, 0);
}

// blocks 0..255: glob ; 256..335: a-frags (jt x s) ; 336..495: wb (sg x q)
__global__ __launch_bounds__(128) void prep_kernel(
    const float* __restrict__ spot_images, const float* __restrict__ W_patch,
    const float* __restrict__ b_patch, const float* __restrict__ W_glob,
    const float* __restrict__ b_glob, const float* __restrict__ W_reg,
    const float* __restrict__ W_emph, const float* __restrict__ b_emph,
    unsigned short* __restrict__ wcomb, float* __restrict__ glob) {
  int bid = blockIdx.x;
  int tid = threadIdx.x;
  if (bid < 256) {
    __shared__ float red[75];
    if (tid < 75) {
      int token = tid / 3;
      int chan = tid - token * 3;
      int ty = token / 5, tx = token - ty * 5;
      const float* img = spot_images + bid * 784 + (ty * 5) * 28 + tx * 5;
      float a = 0.f;
      #pragma unroll
      for (int i = 0; i < 5; ++i)
        #pragma unroll
        for (int j = 0; j < 5; ++j)
          a = fmaf(img[i * 28 + j], W_patch[chan * 25 + i * 5 + j], a);
      a += b_patch[chan];
      red[tid] = a * W_glob[tid];
    }
    __syncthreads();
    if (tid == 0) {
      float s = b_glob[0];
      for (int k = 0; k < 75; ++k) s += red[k];
      glob[bid] = (s > 0.f) ? s : expm1f(s);
    }
  } else if (bid < 336) {
    int idx = bid - 256;               // jt*4 + s
    int jt = idx >> 2, s = idx & 3;
    if (tid < 64) {
      int j = jt * 32 + (tid & 31);
      int h = tid >> 5;
      unsigned short hv[8];
      #pragma unroll
      for (int jj = 0; jj < 8; ++jj) {
        int i = s * 16 + h * 8 + jj;
        float val = 0.f;
        if (j < 625) {
          int ch = j / 25, p = j % 25;
          int oy = p / 5, ox = p - oy * 5;
          if (i < 49) {
            int iy = i / 7, ix = i - iy * 7;
            int ky = iy - oy, kx = ix - ox;
            if (ky >= 0 && ky < 3 && kx >= 0 && kx < 3)
              val = W_emph[ch * 9 + ky * 3 + kx];
          } else if (i == 49) {
            val = b_emph[ch];
          }
        }
        hv[jj] = f2bf(val);
      }
      unsigned int u[4];
      #pragma unroll
      for (int k = 0; k < 4; ++k)
        u[k] = (unsigned int)hv[2 * k] | ((unsigned int)hv[2 * k + 1] << 16);
      ((uint4*)wcomb)[jt * 768 + s * 64 + tid] = make_uint4(u[0], u[1], u[2], u[3]);
    }
  } else {
    int idx = bid - 336;               // sg*4 + q   (sg = kstep 0..39)
    int sg = idx >> 2, q = idx & 3;
    if (tid < 64) {
      int g = q * 32 + (tid & 31);
      int h = tid >> 5;
      unsigned short hv[8];
      #pragma unroll
      for (int jj = 0; jj < 8; ++jj) {
        int k = sg * 16 + h * 8 + jj;
        float val = (g < 117 && k < 625) ? W_reg[g * 625 + k] : 0.f;
        hv[jj] = f2bf(val);
      }
      unsigned int u[4];
      #pragma unroll
      for (int k = 0; k < 4; ++k)
        u[k] = (unsigned int)hv[2 * k] | ((unsigned int)hv[2 * k + 1] << 16);
      int jt = sg >> 1, c = (sg & 1) * 4 + q;   // chunk c = ks*4 + q
      ((uint4*)wcomb)[jt * 768 + 256 + c * 64 + tid] =
          make_uint4(u[0], u[1], u[2], u[3]);
    }
  }
}

// One block = batch b. 768 threads = 12 waves: 0-7 compute, 8-11 out1 stream.
__global__ __launch_bounds__(768, 3) void main_kernel(
    const float* __restrict__ images, const float* __restrict__ b_reg,
    const unsigned short* __restrict__ wcomb, const float* __restrict__ glob,
    float* __restrict__ out) {
  extern __shared__ char smem[];
  unsigned short* imgbs = (unsigned short*)smem;  // 32768 B [8 kc][256 cell][8]
  char* wslab = smem + 32768;                     // 122880 B = 10 jt slabs
  float* redp = (float*)smem;                     // epilogue alias (imgbs dead)
  int tid = threadIdx.x;
  int b = blockIdx.x;
  int l = tid & 63;
  int ct = __builtin_amdgcn_readfirstlane(tid >> 6);   // wave 0..11
  int m = l & 31, hh = l >> 5;
  const char* wcombB = (const char*)wcomb;
  const short8* imgb8 = (const short8*)imgbs;

  float gb = glob[b];
  size_t rowbase = (size_t)b * 512;
  float4 gv = make_float4(gb, gb, gb, gb);
  float4* o1v = (float4*)(out + OUT1_OUT_OFF + rowbase * 117);  // 14976 float4

  // stage 10 jt-slabs (120 KB) for half h: 120 chunks across 12 waves
  auto stage_half = [&](int h) {
    for (int c = ct; c < 120; c += 12)
      gload16(wcombB + h * 122880 + c * 1024 + l * 16, wslab + c * 1024);
  };

  // stage 256 cells (one half) of img -> bf16 chunk-major LDS (768 threads)
  auto stageimg = [&](int hf) {
    for (int u = tid; u < 2048; u += 768) {
      int cell = u & 255, kc = u >> 8;
      const float* src =
          images + (size_t)(b * 512 + hf * 256 + cell) * 49 + kc * 8;
      float v[8];
      #pragma unroll
      for (int j = 0; j < 8; ++j) v[j] = 0.f;
      if (kc < 6) {
        #pragma unroll
        for (int j = 0; j < 8; ++j) v[j] = src[j];
      } else if (kc == 6) {
        v[0] = src[0];
        v[1] = 1.0f;
      }
      unsigned int uu[4];
      #pragma unroll
      for (int k = 0; k < 4; ++k) uu[k] = cvt_pk_bf16(v[2 * k], v[2 * k + 1]);
      ((uint4*)imgbs)[kc * 256 + cell] = make_uint4(uu[0], uu[1], uu[2], uu[3]);
    }
  };

  // persistent img B-frags (compute waves): U = cells ct*64+0..31, V = +32..63
  short8 bU0 = {}, bU1 = {}, bU2 = {}, bU3 = {};
  short8 bV0 = {}, bV1 = {}, bV2 = {}, bV3 = {};
  int base = (ct & 3) * 64;   // local cell base within the half
  stageimg(0);
  __syncthreads();
  if (ct < 4) {
    bU0 = imgb8[(0 + hh) * 256 + base + m];
    bU1 = imgb8[(2 + hh) * 256 + base + m];
    bU2 = imgb8[(4 + hh) * 256 + base + m];
    bU3 = imgb8[(6 + hh) * 256 + base + m];
    bV0 = imgb8[(0 + hh) * 256 + base + 32 + m];
    bV1 = imgb8[(2 + hh) * 256 + base + 32 + m];
    bV2 = imgb8[(4 + hh) * 256 + base + 32 + m];
    bV3 = imgb8[(6 + hh) * 256 + base + 32 + m];
  }
  __syncthreads();
  stageimg(1);
  __syncthreads();
  if (ct >= 4 && ct < 8) {
    bU0 = imgb8[(0 + hh) * 256 + base + m];
    bU1 = imgb8[(2 + hh) * 256 + base + m];
    bU2 = imgb8[(4 + hh) * 256 + base + m];
    bU3 = imgb8[(6 + hh) * 256 + base + m];
    bV0 = imgb8[(0 + hh) * 256 + base + 32 + m];
    bV1 = imgb8[(2 + hh) * 256 + base + 32 + m];
    bV2 = imgb8[(4 + hh) * 256 + base + 32 + m];
    bV3 = imgb8[(6 + hh) * 256 + base + 32 + m];
  }
  stage_half(0);
  __syncthreads();

  f32x16 aU0, aU1, aU2, aU3, aV0, aV1, aV2, aV3;
  #pragma unroll
  for (int i = 0; i < 16; ++i) {
    aU0[i] = 0.f; aU1[i] = 0.f; aU2[i] = 0.f; aU3[i] = 0.f;
    aV0[i] = 0.f; aV1[i] = 0.f; aV2[i] = 0.f; aV3[i] = 0.f;
  }

  auto body = [&](int jl) {
    const short8* wB = (const short8*)(wslab + jl * 12288);
    short8 a0 = wB[l];
    short8 a1 = wB[64 + l];
    short8 a2 = wB[128 + l];
    short8 a3 = wB[192 + l];

    // conv U then pack
    f32x16 o;
    #pragma unroll
    for (int i = 0; i < 16; ++i) o[i] = 0.f;
    o = __builtin_amdgcn_mfma_f32_32x32x16_bf16(a0, bU0, o, 0, 0, 0);
    o = __builtin_amdgcn_mfma_f32_32x32x16_bf16(a1, bU1, o, 0, 0, 0);
    o = __builtin_amdgcn_mfma_f32_32x32x16_bf16(a2, bU2, o, 0, 0, 0);
    o = __builtin_amdgcn_mfma_f32_32x32x16_bf16(a3, bU3, o, 0, 0, 0);
    unsigned int W[8];
    #pragma unroll
    for (int q = 0; q < 8; ++q)
      W[q] = cvt_pk_bf16(fmaxf(o[2 * q], 0.f), fmaxf(o[2 * q + 1], 0.f));
    uint2v s02 = __builtin_amdgcn_permlane32_swap(W[0], W[2], false, false);
    uint2v s13 = __builtin_amdgcn_permlane32_swap(W[1], W[3], false, false);
    uint2v s46 = __builtin_amdgcn_permlane32_swap(W[4], W[6], false, false);
    uint2v s57 = __builtin_amdgcn_permlane32_swap(W[5], W[7], false, false);
    uint4v f0 = {s02[0], s13[0], s02[1], s13[1]};
    uint4v f1 = {s46[0], s57[0], s46[1], s57[1]};
    short8 afU0 = __builtin_bit_cast(short8, f0);
    short8 afU1 = __builtin_bit_cast(short8, f1);

    // conv V then pack
    #pragma unroll
    for (int i = 0; i < 16; ++i) o[i] = 0.f;
    o = __builtin_amdgcn_mfma_f32_32x32x16_bf16(a0, bV0, o, 0, 0, 0);
    o = __builtin_amdgcn_mfma_f32_32x32x16_bf16(a1, bV1, o, 0, 0, 0);
    o = __builtin_amdgcn_mfma_f32_32x32x16_bf16(a2, bV2, o, 0, 0, 0);
    o = __builtin_amdgcn_mfma_f32_32x32x16_bf16(a3, bV3, o, 0, 0, 0);
    #pragma unroll
    for (int q = 0; q < 8; ++q)
      W[q] = cvt_pk_bf16(fmaxf(o[2 * q], 0.f), fmaxf(o[2 * q + 1], 0.f));
    s02 = __builtin_amdgcn_permlane32_swap(W[0], W[2], false, false);
    s13 = __builtin_amdgcn_permlane32_swap(W[1], W[3], false, false);
    s46 = __builtin_amdgcn_permlane32_swap(W[4], W[6], false, false);
    s57 = __builtin_amdgcn_permlane32_swap(W[5], W[7], false, false);
    uint4v g0 = {s02[0], s13[0], s02[1], s13[1]};
    uint4v g1 = {s46[0], s57[0], s46[1], s57[1]};
    short8 afV0 = __builtin_bit_cast(short8, g0);
    short8 afV1 = __builtin_bit_cast(short8, g1);

    // mm2: each wb chunk read once, used for both U and V
    #define MM2(c, AFU, AFV, AU, AV)                                        \
      {                                                                     \
        short8 w = wB[256 + (c)*64 + l];                                    \
        AU = __builtin_amdgcn_mfma_f32_32x32x16_bf16(AFU, w, AU, 0, 0, 0);  \
        AV = __builtin_amdgcn_mfma_f32_32x32x16_bf16(AFV, w, AV, 0, 0, 0);  \
      }
    MM2(0, afU0, afV0, aU0, aV0)
    MM2(1, afU0, afV0, aU1, aV1)
    MM2(2, afU0, afV0, aU2, aV2)
    MM2(3, afU0, afV0, aU3, aV3)
    MM2(4, afU1, afV1, aU0, aV0)
    MM2(5, afU1, afV1, aU1, aV1)
    MM2(6, afU1, afV1, aU2, aV2)
    MM2(7, afU1, afV1, aU3, aV3)
    #undef MM2
  };

  // run 1: compute waves do jt 0-9; streamer waves pump out1 first half
  if (ct < 8) {
    for (int jl = 0; jl < 10; ++jl) body(jl);
  } else {
    int sid = tid - 512;   // 0..255
    for (int i = sid; i < 7488; i += 256) o1v[i] = gv;
  }
  __syncthreads();                // wslab half-0 reads done
  stage_half(1);
  __syncthreads();                // wslab half-1 ready
  // run 2: compute waves do jt 10-19; streamers pump out1 second half
  if (ct < 8) {
    for (int jl = 0; jl < 10; ++jl) body(jl);
  } else {
    int sid = tid - 512;
    for (int i = 7488 + sid; i < 14976; i += 256) o1v[i] = gv;
  }

  // hoisted bias per gene quad
  float br0 = b_reg[m];
  float br1 = b_reg[32 + m];
  float br2 = b_reg[64 + m];
  float br3 = (96 + m < 117) ? b_reg[96 + m] : 0.f;

  // ---- spot from registers: per quad, sum relu over this wave's 64 cells
  if (ct < 8) {
    auto rsum = [&](const f32x16& AU, const f32x16& AV, float br) {
      float s = 0.f;
      #pragma unroll
      for (int reg = 0; reg < 16; ++reg)
        s += fmaxf(AU[reg] + br + gb, 0.f) + fmaxf(AV[reg] + br + gb, 0.f);
      s += __shfl_xor(s, 32, 64);
      return s;
    };
    float s0 = rsum(aU0, aV0, br0);
    float s1 = rsum(aU1, aV1, br1);
    float s2 = rsum(aU2, aV2, br2);
    float s3 = rsum(aU3, aV3, br3);
    if (hh == 0) {
      redp[ct * 128 + m] = s0;
      redp[ct * 128 + 32 + m] = s1;
      redp[ct * 128 + 64 + m] = s2;
      redp[ct * 128 + 96 + m] = s3;
    }
  }
  __syncthreads();   // redp complete (the ONLY epilogue barrier)
  if (tid < 117) {
    float s = 0.f;
    #pragma unroll
    for (int w = 0; w < 8; ++w) s += redp[w * 128 + tid];
    out[SPOT_OUT_OFF + b * 117 + tid] = s;
  }

  // ---- direct cell stores from accumulators (compute waves only) ----
  // row n = ct*64 + S*32 + 4*hh + 8*(r>>2) + (r&3); col g = q*32+m.
  if (ct < 8) {
    bool q3ok = (m < 21);
    float* cbase = out + CELL_OUT_OFF + (rowbase + ct * 64 + 4 * hh) * 117 + m;
    #pragma unroll
    for (int G = 0; G < 4; ++G) {
      float* pU = cbase + (8 * G) * 117;
      float* pV = pU + 32 * 117;
      #pragma unroll
      for (int rr = 0; rr < 4; ++rr) {
        int r = G * 4 + rr;
        int ro = rr * 117;
        pU[ro] = fmaxf(aU0[r] + br0 + gb, 0.f);
        pU[ro + 32] = fmaxf(aU1[r] + br1 + gb, 0.f);
        pU[ro + 64] = fmaxf(aU2[r] + br2 + gb, 0.f);
        if (q3ok) pU[ro + 96] = fmaxf(aU3[r] + br3 + gb, 0.f);
        pV[ro] = fmaxf(aV0[r] + br0 + gb, 0.f);
        pV[ro + 32] = fmaxf(aV1[r] + br1 + gb, 0.f);
        pV[ro + 64] = fmaxf(aV2[r] + br2 + gb, 0.f);
        if (q3ok) pV[ro + 96] = fmaxf(aV3[r] + br3 + gb, 0.f);
      }
    }
  }
}

extern "C" void kernel_launch(void* const* d_in, const int* in_sizes, int n_in,
                              void* d_out, int out_size, void* d_ws, size_t ws_size,
                              hipStream_t stream) {
  const float* images      = (const float*)d_in[0];
  const float* spot_images = (const float*)d_in[1];
  // d_in[2] = gene_expression (unused by the reference)
  const float* W_emph = (const float*)d_in[3];
  const float* b_emph = (const float*)d_in[4];
  const float* W_reg  = (const float*)d_in[5];
  const float* b_reg  = (const float*)d_in[6];
  const float* W_patch = (const float*)d_in[7];
  const float* b_patch = (const float*)d_in[8];
  const float* W_glob  = (const float*)d_in[9];
  const float* b_glob  = (const float*)d_in[10];
  float* out = (float*)d_out;

  unsigned short* wcomb = (unsigned short*)((char*)d_ws + WCOMB_OFF);
  float* glob  = (float*)((char*)d_ws + GLOB_OFF);

  (void)hipFuncSetAttribute((const void*)main_kernel,
                            hipFuncAttributeMaxDynamicSharedMemorySize,
                            SMEM_BYTES);

  prep_kernel<<<496, 128, 0, stream>>>(spot_images, W_patch, b_patch, W_glob,
                                       b_glob, W_reg, W_emph, b_emph, wcomb,
                                       glob);
  main_kernel<<<256, 768, SMEM_BYTES, stream>>>(images, b_reg, wcomb, glob,
                                                out);
}

// Round 18
// 51.281 us; speedup vs baseline: 5.3824x; 5.3824x over previous
//
#include <hip/hip_runtime.h>

// B=256, N=512 cells, G=117 genes, CH=25 conv channels.
// One block = one batch (512 cells), grid 256 = 1 block/CU, 8 waves; wave owns
// 64 cells (U/V subtiles of 32) x all 128 genes. Conv-as-MFMA with register
// handoff (cvt_pk + permlane32_swap) into the regression MFMAs.
// BARRIER-MINIMAL: weights staged in two 120KB mega-slabs (10 jt each) into
// 155KB dynamic LDS -> inner 10-jt runs have ZERO barriers (waves drift,
// compiler pipelines across jt). Spot reduced in registers. Epilogue uses two
// 64KB ping-pong C buffers (128 cells/round, 4 barriers total).
// out1 streamed during the K loop; cell stores paced across epilogue rounds.
// [r18 = revert to r12, the empirical optimum of rounds 10-17.]

typedef __attribute__((ext_vector_type(16))) float f32x16;
typedef __attribute__((ext_vector_type(8))) short short8;
typedef __attribute__((ext_vector_type(2))) unsigned int uint2v;
typedef __attribute__((ext_vector_type(4))) unsigned int uint4v;

#define WCOMB_OFF 0          // 245760 B : [20 jt][12288 B = 4KB a | 8KB wb]
#define GLOB_OFF  245760     // 1024 B   : glob[256]

#define SPOT_OUT_OFF 0
#define CELL_OUT_OFF 29952
#define OUT1_OUT_OFF 15365376

#define SMEM_BYTES 155648    // imgbs 32768 + wslab 122880

__device__ __forceinline__ unsigned short f2bf(float x) {
  unsigned int u = __builtin_bit_cast(unsigned int, x);
  u = (u + 0x7FFFu + ((u >> 16) & 1u)) >> 16;   // RNE
  return (unsigned short)u;
}

__device__ __forceinline__ unsigned int cvt_pk_bf16(float lo, float hi) {
  unsigned int w;
  asm("v_cvt_pk_bf16_f32 %0, %1, %2" : "=v"(w) : "v"(lo), "v"(hi));
  return w;
}

__device__ __forceinline__ void gload16(const void* g, void* l) {
  __builtin_amdgcn_global_load_lds(
      (const __attribute__((address_space(1))) void*)g,
      (__attribute__((address_space(3))) void*)l, 16, 0, 0);
}

// blocks 0..255: glob ; 256..335: a-frags (jt x s) ; 336..495: wb (sg x q)
__global__ __launch_bounds__(128) void prep_kernel(
    const float* __restrict__ spot_images, const float* __restrict__ W_patch,
    const float* __restrict__ b_patch, const float* __restrict__ W_glob,
    const float* __restrict__ b_glob, const float* __restrict__ W_reg,
    const float* __restrict__ W_emph, const float* __restrict__ b_emph,
    unsigned short* __restrict__ wcomb, float* __restrict__ glob) {
  int bid = blockIdx.x;
  int tid = threadIdx.x;
  if (bid < 256) {
    __shared__ float red[75];
    if (tid < 75) {
      int token = tid / 3;
      int chan = tid - token * 3;
      int ty = token / 5, tx = token - ty * 5;
      const float* img = spot_images + bid * 784 + (ty * 5) * 28 + tx * 5;
      float a = 0.f;
      #pragma unroll
      for (int i = 0; i < 5; ++i)
        #pragma unroll
        for (int j = 0; j < 5; ++j)
          a = fmaf(img[i * 28 + j], W_patch[chan * 25 + i * 5 + j], a);
      a += b_patch[chan];
      red[tid] = a * W_glob[tid];
    }
    __syncthreads();
    if (tid == 0) {
      float s = b_glob[0];
      for (int k = 0; k < 75; ++k) s += red[k];
      glob[bid] = (s > 0.f) ? s : expm1f(s);
    }
  } else if (bid < 336) {
    int idx = bid - 256;               // jt*4 + s
    int jt = idx >> 2, s = idx & 3;
    if (tid < 64) {
      int j = jt * 32 + (tid & 31);
      int h = tid >> 5;
      unsigned short hv[8];
      #pragma unroll
      for (int jj = 0; jj < 8; ++jj) {
        int i = s * 16 + h * 8 + jj;
        float val = 0.f;
        if (j < 625) {
          int ch = j / 25, p = j % 25;
          int oy = p / 5, ox = p - oy * 5;
          if (i < 49) {
            int iy = i / 7, ix = i - iy * 7;
            int ky = iy - oy, kx = ix - ox;
            if (ky >= 0 && ky < 3 && kx >= 0 && kx < 3)
              val = W_emph[ch * 9 + ky * 3 + kx];
          } else if (i == 49) {
            val = b_emph[ch];
          }
        }
        hv[jj] = f2bf(val);
      }
      unsigned int u[4];
      #pragma unroll
      for (int k = 0; k < 4; ++k)
        u[k] = (unsigned int)hv[2 * k] | ((unsigned int)hv[2 * k + 1] << 16);
      ((uint4*)wcomb)[jt * 768 + s * 64 + tid] = make_uint4(u[0], u[1], u[2], u[3]);
    }
  } else {
    int idx = bid - 336;               // sg*4 + q   (sg = kstep 0..39)
    int sg = idx >> 2, q = idx & 3;
    if (tid < 64) {
      int g = q * 32 + (tid & 31);
      int h = tid >> 5;
      unsigned short hv[8];
      #pragma unroll
      for (int jj = 0; jj < 8; ++jj) {
        int k = sg * 16 + h * 8 + jj;
        float val = (g < 117 && k < 625) ? W_reg[g * 625 + k] : 0.f;
        hv[jj] = f2bf(val);
      }
      unsigned int u[4];
      #pragma unroll
      for (int k = 0; k < 4; ++k)
        u[k] = (unsigned int)hv[2 * k] | ((unsigned int)hv[2 * k + 1] << 16);
      int jt = sg >> 1, c = (sg & 1) * 4 + q;   // chunk c = ks*4 + q
      ((uint4*)wcomb)[jt * 768 + 256 + c * 64 + tid] =
          make_uint4(u[0], u[1], u[2], u[3]);
    }
  }
}

// One block = batch b (512 cells). 512 threads = 8 waves (ct = 64-cell group).
__global__ __launch_bounds__(512, 2) void main_kernel(
    const float* __restrict__ images, const float* __restrict__ b_reg,
    const unsigned short* __restrict__ wcomb, const float* __restrict__ glob,
    float* __restrict__ out) {
  extern __shared__ char smem[];
  unsigned short* imgbs = (unsigned short*)smem;  // 32768 B [8 kc][256 cell][8]
  char* wslab = smem + 32768;                     // 122880 B = 10 jt slabs
  float* C0 = (float*)smem;                       // 65536 B [128][128] (epi)
  float* C1 = (float*)(smem + 65536);             // 65536 B
  float* redp = (float*)(smem + 131072);          // 4096 B [8][128]
  int tid = threadIdx.x;
  int b = blockIdx.x;
  int l = tid & 63;
  int ct = __builtin_amdgcn_readfirstlane(tid >> 6);   // wave 0..7
  int m = l & 31, hh = l >> 5;
  const char* wcombB = (const char*)wcomb;
  const short8* imgb8 = (const short8*)imgbs;

  float gb = glob[b];
  size_t rowbase = (size_t)b * 512;
  float4 gv = make_float4(gb, gb, gb, gb);
  float4* o1v = (float4*)(out + OUT1_OUT_OFF + rowbase * 117);  // 14976 float4

  // stage 10 jt-slabs (120 KB) for half h: 120 wave-chunks of 1KB
  auto stage_half = [&](int h) {
    #pragma unroll
    for (int i = 0; i < 15; ++i) {
      int c = ct + 8 * i;
      gload16(wcombB + h * 122880 + c * 1024 + l * 16, wslab + c * 1024);
    }
  };

  // stage 256 cells (one half) of img -> bf16 chunk-major LDS
  auto stageimg = [&](int hf) {
    #pragma unroll
    for (int it = 0; it < 4; ++it) {
      int u = it * 512 + tid;
      int cell = u & 255, kc = u >> 8;
      const float* src =
          images + (size_t)(b * 512 + hf * 256 + cell) * 49 + kc * 8;
      float v[8];
      #pragma unroll
      for (int j = 0; j < 8; ++j) v[j] = 0.f;
      if (kc < 6) {
        #pragma unroll
        for (int j = 0; j < 8; ++j) v[j] = src[j];
      } else if (kc == 6) {
        v[0] = src[0];
        v[1] = 1.0f;
      }
      unsigned int uu[4];
      #pragma unroll
      for (int k = 0; k < 4; ++k) uu[k] = cvt_pk_bf16(v[2 * k], v[2 * k + 1]);
      ((uint4*)imgbs)[kc * 256 + cell] = make_uint4(uu[0], uu[1], uu[2], uu[3]);
    }
  };

  // persistent img B-frags: subtile U = cells ct*64+0..31, V = +32..63
  short8 bU0, bU1, bU2, bU3, bV0, bV1, bV2, bV3;
  int base = (ct & 3) * 64;   // local cell base within the half
  stageimg(0);
  __syncthreads();
  if (ct < 4) {
    bU0 = imgb8[(0 + hh) * 256 + base + m];
    bU1 = imgb8[(2 + hh) * 256 + base + m];
    bU2 = imgb8[(4 + hh) * 256 + base + m];
    bU3 = imgb8[(6 + hh) * 256 + base + m];
    bV0 = imgb8[(0 + hh) * 256 + base + 32 + m];
    bV1 = imgb8[(2 + hh) * 256 + base + 32 + m];
    bV2 = imgb8[(4 + hh) * 256 + base + 32 + m];
    bV3 = imgb8[(6 + hh) * 256 + base + 32 + m];
  }
  __syncthreads();
  stageimg(1);
  __syncthreads();
  if (ct >= 4) {
    bU0 = imgb8[(0 + hh) * 256 + base + m];
    bU1 = imgb8[(2 + hh) * 256 + base + m];
    bU2 = imgb8[(4 + hh) * 256 + base + m];
    bU3 = imgb8[(6 + hh) * 256 + base + m];
    bV0 = imgb8[(0 + hh) * 256 + base + 32 + m];
    bV1 = imgb8[(2 + hh) * 256 + base + 32 + m];
    bV2 = imgb8[(4 + hh) * 256 + base + 32 + m];
    bV3 = imgb8[(6 + hh) * 256 + base + 32 + m];
  }
  stage_half(0);
  __syncthreads();

  f32x16 aU0, aU1, aU2, aU3, aV0, aV1, aV2, aV3;
  #pragma unroll
  for (int i = 0; i < 16; ++i) {
    aU0[i] = 0.f; aU1[i] = 0.f; aU2[i] = 0.f; aU3[i] = 0.f;
    aV0[i] = 0.f; aV1[i] = 0.f; aV2[i] = 0.f; aV3[i] = 0.f;
  }

  auto body = [&](int jl, int jt) {
    if (jt < 15) {                              // out1 stream during compute
      int i0 = jt * 1024 + tid;
      o1v[i0] = gv;
      int i1 = i0 + 512;
      if (i1 < 14976) o1v[i1] = gv;
    }
    const short8* wB = (const short8*)(wslab + jl * 12288);
    short8 a0 = wB[l];
    short8 a1 = wB[64 + l];
    short8 a2 = wB[128 + l];
    short8 a3 = wB[192 + l];

    // conv U then pack
    f32x16 o;
    #pragma unroll
    for (int i = 0; i < 16; ++i) o[i] = 0.f;
    o = __builtin_amdgcn_mfma_f32_32x32x16_bf16(a0, bU0, o, 0, 0, 0);
    o = __builtin_amdgcn_mfma_f32_32x32x16_bf16(a1, bU1, o, 0, 0, 0);
    o = __builtin_amdgcn_mfma_f32_32x32x16_bf16(a2, bU2, o, 0, 0, 0);
    o = __builtin_amdgcn_mfma_f32_32x32x16_bf16(a3, bU3, o, 0, 0, 0);
    unsigned int W[8];
    #pragma unroll
    for (int q = 0; q < 8; ++q)
      W[q] = cvt_pk_bf16(fmaxf(o[2 * q], 0.f), fmaxf(o[2 * q + 1], 0.f));
    uint2v s02 = __builtin_amdgcn_permlane32_swap(W[0], W[2], false, false);
    uint2v s13 = __builtin_amdgcn_permlane32_swap(W[1], W[3], false, false);
    uint2v s46 = __builtin_amdgcn_permlane32_swap(W[4], W[6], false, false);
    uint2v s57 = __builtin_amdgcn_permlane32_swap(W[5], W[7], false, false);
    uint4v f0 = {s02[0], s13[0], s02[1], s13[1]};
    uint4v f1 = {s46[0], s57[0], s46[1], s57[1]};
    short8 afU0 = __builtin_bit_cast(short8, f0);
    short8 afU1 = __builtin_bit_cast(short8, f1);

    // conv V then pack
    #pragma unroll
    for (int i = 0; i < 16; ++i) o[i] = 0.f;
    o = __builtin_amdgcn_mfma_f32_32x32x16_bf16(a0, bV0, o, 0, 0, 0);
    o = __builtin_amdgcn_mfma_f32_32x32x16_bf16(a1, bV1, o, 0, 0, 0);
    o = __builtin_amdgcn_mfma_f32_32x32x16_bf16(a2, bV2, o, 0, 0, 0);
    o = __builtin_amdgcn_mfma_f32_32x32x16_bf16(a3, bV3, o, 0, 0, 0);
    #pragma unroll
    for (int q = 0; q < 8; ++q)
      W[q] = cvt_pk_bf16(fmaxf(o[2 * q], 0.f), fmaxf(o[2 * q + 1], 0.f));
    s02 = __builtin_amdgcn_permlane32_swap(W[0], W[2], false, false);
    s13 = __builtin_amdgcn_permlane32_swap(W[1], W[3], false, false);
    s46 = __builtin_amdgcn_permlane32_swap(W[4], W[6], false, false);
    s57 = __builtin_amdgcn_permlane32_swap(W[5], W[7], false, false);
    uint4v g0 = {s02[0], s13[0], s02[1], s13[1]};
    uint4v g1 = {s46[0], s57[0], s46[1], s57[1]};
    short8 afV0 = __builtin_bit_cast(short8, g0);
    short8 afV1 = __builtin_bit_cast(short8, g1);

    // mm2: each wb chunk read once, used for both U and V
    #define MM2(c, AFU, AFV, AU, AV)                                        \
      {                                                                     \
        short8 w = wB[256 + (c)*64 + l];                                    \
        AU = __builtin_amdgcn_mfma_f32_32x32x16_bf16(AFU, w, AU, 0, 0, 0);  \
        AV = __builtin_amdgcn_mfma_f32_32x32x16_bf16(AFV, w, AV, 0, 0, 0);  \
      }
    MM2(0, afU0, afV0, aU0, aV0)
    MM2(1, afU0, afV0, aU1, aV1)
    MM2(2, afU0, afV0, aU2, aV2)
    MM2(3, afU0, afV0, aU3, aV3)
    MM2(4, afU1, afV1, aU0, aV0)
    MM2(5, afU1, afV1, aU1, aV1)
    MM2(6, afU1, afV1, aU2, aV2)
    MM2(7, afU1, afV1, aU3, aV3)
    #undef MM2
  };

  for (int jl = 0; jl < 10; ++jl) body(jl, jl);          // no barriers inside
  __syncthreads();                                        // wslab reads done
  stage_half(1);
  __syncthreads();
  for (int jl = 0; jl < 10; ++jl) body(jl, 10 + jl);
  __syncthreads();                                        // loop fully done

  // hoisted bias per gene quad
  float br0 = (0 * 32 + m < 117) ? b_reg[0 * 32 + m] : 0.f;
  float br1 = b_reg[32 + m];
  float br2 = b_reg[64 + m];
  float br3 = (96 + m < 117) ? b_reg[96 + m] : 0.f;

  // ---- spot from registers: per quad, sum relu over this wave's 64 cells
  {
    auto rsum = [&](const f32x16& AU, const f32x16& AV, float br) {
      float s = 0.f;
      #pragma unroll
      for (int reg = 0; reg < 16; ++reg)
        s += fmaxf(AU[reg] + br + gb, 0.f) + fmaxf(AV[reg] + br + gb, 0.f);
      s += __shfl_xor(s, 32, 64);
      return s;
    };
    float s0 = rsum(aU0, aV0, br0);
    float s1 = rsum(aU1, aV1, br1);
    float s2 = rsum(aU2, aV2, br2);
    float s3 = rsum(aU3, aV3, br3);
    if (hh == 0) {
      redp[ct * 128 + m] = s0;
      redp[ct * 128 + 32 + m] = s1;
      redp[ct * 128 + 64 + m] = s2;
      redp[ct * 128 + 96 + m] = s3;
    }
  }

  // ---- epilogue: 4 rounds of 128 cells, ping-pong C0/C1 ----
  #define EPI(Cb, Q, ACC, NB, BR)                                          \
    {                                                                      \
      int g = (Q)*32 + m;                                                  \
      _Pragma("unroll")                                                    \
      for (int reg = 0; reg < 16; ++reg) {                                 \
        int n = (NB) + (reg & 3) + 8 * (reg >> 2) + 4 * hh;                \
        (Cb)[n * 128 + g] = fmaxf(ACC[reg] + (BR) + gb, 0.f);              \
      }                                                                    \
    }
  #define EPIW(Cb, e)                                                      \
    {                                                                      \
      int nb = (e)*64;                                                     \
      EPI(Cb, 0, aU0, nb, br0) EPI(Cb, 1, aU1, nb, br1)                    \
      EPI(Cb, 2, aU2, nb, br2) EPI(Cb, 3, aU3, nb, br3)                    \
      EPI(Cb, 0, aV0, nb + 32, br0) EPI(Cb, 1, aV1, nb + 32, br1)          \
      EPI(Cb, 2, aV2, nb + 32, br2) EPI(Cb, 3, aV3, nb + 32, br3)          \
    }
  auto streamC = [&](const float* Cb, int r) {
    float* cellchunk = out + CELL_OUT_OFF + (rowbase + r * 128) * 117;
    #pragma unroll
    for (int i = 0; i < 30; ++i) {
      int idx = i * 512 + tid;
      if (idx < 14976) {
        int n = idx / 117;
        int gg = idx - n * 117;
        cellchunk[idx] = Cb[n * 128 + gg];
      }
    }
  };

  // round 0 written by waves 0,1
  if (ct < 2) EPIW(C0, ct & 1);
  __syncthreads();
  // spot finalize (redp stable from here on)
  if (tid < 117) {
    float s = 0.f;
    #pragma unroll
    for (int w = 0; w < 8; ++w) s += redp[w * 128 + tid];
    out[SPOT_OUT_OFF + b * 117 + tid] = s;
  }
  if (ct == 2 || ct == 3) EPIW(C1, ct & 1);   // round 1
  streamC(C0, 0);
  __syncthreads();
  if (ct == 4 || ct == 5) EPIW(C0, ct & 1);   // round 2
  streamC(C1, 1);
  __syncthreads();
  if (ct == 6 || ct == 7) EPIW(C1, ct & 1);   // round 3
  streamC(C0, 2);
  __syncthreads();
  streamC(C1, 3);
  #undef EPIW
  #undef EPI
}

extern "C" void kernel_launch(void* const* d_in, const int* in_sizes, int n_in,
                              void* d_out, int out_size, void* d_ws, size_t ws_size,
                              hipStream_t stream) {
  const float* images      = (const float*)d_in[0];
  const float* spot_images = (const float*)d_in[1];
  // d_in[2] = gene_expression (unused by the reference)
  const float* W_emph = (const float*)d_in[3];
  const float* b_emph = (const float*)d_in[4];
  const float* W_reg  = (const float*)d_in[5];
  const float* b_reg  = (const float*)d_in[6];
  const float* W_patch = (const float*)d_in[7];
  const float* b_patch = (const float*)d_in[8];
  const float* W_glob  = (const float*)d_in[9];
  const float* b_glob  = (const float*)d_in[10];
  float* out = (float*)d_out;

  unsigned short* wcomb = (unsigned short*)((char*)d_ws + WCOMB_OFF);
  float* glob  = (float*)((char*)d_ws + GLOB_OFF);

  (void)hipFuncSetAttribute((const void*)main_kernel,
                            hipFuncAttributeMaxDynamicSharedMemorySize,
                            SMEM_BYTES);

  prep_kernel<<<496, 128, 0, stream>>>(spot_images, W_patch, b_patch, W_glob,
                                       b_glob, W_reg, W_emph, b_emph, wcomb,
                                       glob);
  main_kernel<<<256, 512, SMEM_BYTES, stream>>>(images, b_reg, wcomb, glob,
                                                out);
}